// Round 7
// baseline (118.395 us; speedup 1.0000x reference)
//
#include <hip/hip_runtime.h>
#include <math.h>

#define L_SEQ 8192
#define B_N   8

typedef float f4v __attribute__((ext_vector_type(4)));

// Workspace layout (float offsets); ~12.3 MB used.
#define QKV_OFF    0                        // [8][512] = 4096 (pre-scaled by 0.125)
#define V_OFF      4096                     // [8][512] = 4096
#define ROW_OFF    8192                     // [8][512] = 4096
#define QFP_OFF    12288                    // [53][512] = 27136 (qf partials)
#define DPART_OFF  40960                    // [768 slots][8] = 6144
#define YPART_OFF  65536                    // [768 slots][4096] = 3145728

// ---- k2: self-contained qf partials: recompute qraw slice in-block, no atomics ----
__global__ __launch_bounds__(512) void k2_qf(const float* __restrict__ poi,
                                             const float* __restrict__ wq1,
                                             const float* __restrict__ bq1,
                                             const float* __restrict__ wq2, float* ws) {
    __shared__ float qr[32];
    int k = blockIdx.x, t = threadIdx.x;
    int i0 = k * 32;
    int cnt = 1683 - i0; if (cnt > 32) cnt = 32;
    if (t < cnt) {
        float a = bq1[0];
#pragma unroll
        for (int j = 0; j < 24; ++j) a += poi[(i0 + t) * 24 + j] * wq1[j];
        qr[t] = a;
    }
    __syncthreads();
    float a = 0.f;
    for (int ii = 0; ii < cnt; ++ii) a += qr[ii] * wq2[(size_t)(i0 + ii) * 512 + t];
    ws[QFP_OFF + k * 512 + t] = a;
}

// ---- k3: qf = bq2 + sum partials; qkvec (pre-scaled); blocks 0-7 init V=bv, 8-15 row=bo ----
__global__ void k3_qkvec(const float* __restrict__ wk, const float* __restrict__ bq2,
                         const float* __restrict__ bv, const float* __restrict__ bo, float* ws) {
    __shared__ float qf[512];
    int t = threadIdx.x, bid = blockIdx.x;
    for (int o = t; o < 512; o += 256) {
        float s = bq2[o];
        for (int k = 0; k < 53; ++k) s += ws[QFP_OFF + k * 512 + o];
        qf[o] = s;
    }
    __syncthreads();
    int idx = bid * 256 + t;
    int h = idx >> 9, c = idx & 511;
    float a = 0.f;
#pragma unroll 8
    for (int e = 0; e < 64; ++e) a += qf[h * 64 + e] * wk[(size_t)c * 512 + h * 64 + e];
    ws[QKV_OFF + idx] = 0.125f * a;
    // bias inits (V, row) — ready before kV/kRow
    if (bid < 8) {
        ws[V_OFF + bid * 512 + t]       = bv[t];
        ws[V_OFF + bid * 512 + 256 + t] = bv[256 + t];
    } else {
        int b = bid - 8;
        ws[ROW_OFF + b * 512 + t]       = bo[t];
        ws[ROW_OFF + b * 512 + 256 + t] = bo[256 + t];
    }
}

// ---- kF: fused pass (dot -> butterfly -> exp -> weighted accumulate); 3 waves/SIMD ----
// ck dropped: per-head constant cancels in softmax.
__global__ __launch_bounds__(256, 3) void kF(const float* __restrict__ x, float* __restrict__ ws) {
    int t = threadIdx.x;
    int lane = t & 63, w = t >> 6;
    int b = blockIdx.x / 96, slot = blockIdx.x % 96;
    int wslot = slot * 4 + w;                 // 0..383 waves per batch

    float4 qa[8], qb[8];
    const float4* qk4 = (const float4*)(ws + QKV_OFF);
#pragma unroll
    for (int h = 0; h < 8; ++h) {
        qa[h] = qk4[h * 128 + lane * 2];
        qb[h] = qk4[h * 128 + lane * 2 + 1];
    }

    float num[8][8] = {{0.f}};
    float den[8] = {0.f};

    const float4* xp = (const float4*)(x + (size_t)b * L_SEQ * 512);
    float4 cxa = xp[(size_t)wslot * 128 + lane * 2];
    float4 cxb = xp[(size_t)wslot * 128 + lane * 2 + 1];

    for (int r = wslot; r < L_SEQ; r += 384) {
        int rn = r + 384;
        float4 nxa = cxa, nxb = cxb;
        if (rn < L_SEQ) {
            nxa = xp[(size_t)rn * 128 + lane * 2];
            nxb = xp[(size_t)rn * 128 + lane * 2 + 1];
        }
        float p[8];
#pragma unroll
        for (int h = 0; h < 8; ++h)
            p[h] = cxa.x * qa[h].x + cxa.y * qa[h].y + cxa.z * qa[h].z + cxa.w * qa[h].w
                 + cxb.x * qb[h].x + cxb.y * qb[h].y + cxb.z * qb[h].z + cxb.w * qb[h].w;
#pragma unroll
        for (int m = 32; m >= 1; m >>= 1) {
#pragma unroll
            for (int h = 0; h < 8; ++h) p[h] += __shfl_xor(p[h], m, 64);
        }
#pragma unroll
        for (int h = 0; h < 8; ++h) {
            float wg = __expf(p[h]);          // logits pre-scaled by 0.125; |p| small
            den[h] += wg;
            num[h][0] += wg * cxa.x; num[h][1] += wg * cxa.y;
            num[h][2] += wg * cxa.z; num[h][3] += wg * cxa.w;
            num[h][4] += wg * cxb.x; num[h][5] += wg * cxb.y;
            num[h][6] += wg * cxb.z; num[h][7] += wg * cxb.w;
        }
        cxa = nxa; cxb = nxb;
    }

    // staged deterministic block reduction in LDS
    __shared__ float num_s[4096];
    __shared__ float den_s[8];
    for (int wi = 0; wi < 4; ++wi) {
        if (w == wi) {
#pragma unroll
            for (int h = 0; h < 8; ++h) {
                int base = h * 512 + lane * 8;
                if (wi == 0) {
#pragma unroll
                    for (int j = 0; j < 8; ++j) num_s[base + j] = num[h][j];
                    if (lane == 0) den_s[h] = den[h];
                } else {
#pragma unroll
                    for (int j = 0; j < 8; ++j) num_s[base + j] += num[h][j];
                    if (lane == 0) den_s[h] += den[h];
                }
            }
        }
        __syncthreads();
    }
    // coalesced partial-slot store (no atomics)
    float4* yp4 = (float4*)(ws + YPART_OFF + (size_t)blockIdx.x * 4096);
    const float4* ns4 = (const float4*)num_s;
#pragma unroll
    for (int k = 0; k < 4; ++k) yp4[k * 256 + t] = ns4[k * 256 + t];
    if (t < 8) ws[DPART_OFF + blockIdx.x * 8 + t] = den_s[t];
}

// ---- kV: reduce 96 partial slots, normalize, V[b,o] += chunk GEMV (V init'd to bv) ----
__global__ __launch_bounds__(512) void kV(const float* __restrict__ wv, float* ws) {
    __shared__ float red[512];
    __shared__ float yn_s[512];   // [h][64c] for this chunk
    __shared__ float dinv[8];
    int b = blockIdx.x >> 3, cc = blockIdx.x & 7;
    int c0 = cc * 64;
    int t = threadIdx.x;
    // den: 96 slots x 8 heads -> fold slots 64..95 into 0..31, then tree over 64
    {
        int s0 = t >> 3, hh = t & 7;
        const float* dp = ws + DPART_OFF + (size_t)(b * 96) * 8 + hh;
        float v = dp[(size_t)s0 * 8];
        if (s0 < 32) v += dp[(size_t)(64 + s0) * 8];
        red[t] = v;
    }
    __syncthreads();
#pragma unroll
    for (int off = 256; off >= 8; off >>= 1) {
        if (t < off) red[t] += red[t + off];
        __syncthreads();
    }
    if (t < 8) dinv[t] = 1.f / red[t];
    // y: sum 96 slots for this (h, c)
    int h = t >> 6, cl = t & 63;
    float s = 0.f;
    const float* yp = ws + YPART_OFF + (size_t)(b * 96) * 4096 + h * 512 + c0 + cl;
#pragma unroll 8
    for (int sl = 0; sl < 96; ++sl) s += yp[(size_t)sl * 4096];
    __syncthreads();
    yn_s[t] = s * dinv[h];
    __syncthreads();
    int o = t, ho = o >> 6;
    const float* yh = yn_s + ho * 64;
    float acc = 0.f;
#pragma unroll 8
    for (int ci = 0; ci < 64; ++ci) acc += yh[ci] * wv[(size_t)(c0 + ci) * 512 + o];
    atomicAdd(ws + V_OFF + b * 512 + o, acc);
}

// ---- kRow: row[b,j] += sum_{o in chunk} V[b,o]*wo[o,j]  (row init'd to bo) ----
__global__ __launch_bounds__(512) void kRow(const float* __restrict__ wo, float* ws) {
    __shared__ float V_s[64];
    int b = blockIdx.x >> 3, oc = blockIdx.x & 7;
    int o0 = oc * 64;
    int t = threadIdx.x;
    if (t < 64) V_s[t] = ws[V_OFF + b * 512 + o0 + t];
    __syncthreads();
    float acc = 0.f;
#pragma unroll 8
    for (int oi = 0; oi < 64; ++oi) acc += V_s[oi] * wo[(size_t)(o0 + oi) * 512 + t];
    atomicAdd(ws + ROW_OFF + b * 512 + t, acc);
}

// ---- k9: broadcast out[b,l,:] = row[b,:]  (nontemporal float4 stores) ----
__global__ __launch_bounds__(256) void k9_out(const float* __restrict__ ws, float* __restrict__ out) {
    const f4v* row4 = (const f4v*)(ws + ROW_OFF);
    f4v* out4 = (f4v*)out;
    size_t stride = (size_t)gridDim.x * blockDim.x;
    for (size_t g = (size_t)blockIdx.x * blockDim.x + threadIdx.x; g < 8388608ull; g += stride) {
        int b = (int)(g >> 20);          // 8192 rows * 128 float4/row = 2^20 per batch
        int q = (int)(g & 127);
        f4v v = row4[b * 128 + q];
        __builtin_nontemporal_store(v, &out4[g]);
    }
}

extern "C" void kernel_launch(void* const* d_in, const int* in_sizes, int n_in,
                              void* d_out, int out_size, void* d_ws, size_t ws_size,
                              hipStream_t stream) {
    const float* x   = (const float*)d_in[0];
    const float* poi = (const float*)d_in[1];
    const float* wq1 = (const float*)d_in[2];
    const float* bq1 = (const float*)d_in[3];
    const float* wq2 = (const float*)d_in[4];
    const float* bq2 = (const float*)d_in[5];
    const float* wk  = (const float*)d_in[6];
    const float* bk  = (const float*)d_in[7];
    const float* wv  = (const float*)d_in[8];
    const float* bv  = (const float*)d_in[9];
    const float* wo  = (const float*)d_in[10];
    const float* bo  = (const float*)d_in[11];
    float* ws  = (float*)d_ws;
    float* out = (float*)d_out;
    (void)bk;

    k2_qf<<<53, 512, 0, stream>>>(poi, wq1, bq1, wq2, ws);
    k3_qkvec<<<16, 256, 0, stream>>>(wk, bq2, bv, bo, ws);
    kF<<<768, 256, 0, stream>>>(x, ws);
    kV<<<64, 512, 0, stream>>>(wv, ws);
    kRow<<<64, 512, 0, stream>>>(wo, ws);
    k9_out<<<2048, 256, 0, stream>>>(ws, out);
}

// Round 8
// 101.282 us; speedup vs baseline: 1.1690x; 1.1690x over previous
//
#include <hip/hip_runtime.h>
#include <math.h>

#define L_SEQ 8192
#define B_N   8

typedef float f4v __attribute__((ext_vector_type(4)));

// Workspace layout (float offsets); ~8.7 MB used.
#define QKV_OFF    0                        // [8][512] = 4096 (pre-scaled by 0.125)
#define V_OFF      4096                     // [8][512] = 4096
#define ROW_OFF    8192                     // [8][512] = 4096
#define QFP_OFF    12288                    // [53][512] = 27136 (qf partials)
#define DPART_OFF  40960                    // [512 slots][8] = 4096
#define YPART_OFF  65536                    // [512 slots][4096] = 2097152

// ---- k2: self-contained qf partials: recompute qraw slice in-block, no atomics ----
__global__ __launch_bounds__(512) void k2_qf(const float* __restrict__ poi,
                                             const float* __restrict__ wq1,
                                             const float* __restrict__ bq1,
                                             const float* __restrict__ wq2, float* ws) {
    __shared__ float qr[32];
    int k = blockIdx.x, t = threadIdx.x;
    int i0 = k * 32;
    int cnt = 1683 - i0; if (cnt > 32) cnt = 32;
    if (t < cnt) {
        float a = bq1[0];
#pragma unroll
        for (int j = 0; j < 24; ++j) a += poi[(i0 + t) * 24 + j] * wq1[j];
        qr[t] = a;
    }
    __syncthreads();
    float a = 0.f;
    for (int ii = 0; ii < cnt; ++ii) a += qr[ii] * wq2[(size_t)(i0 + ii) * 512 + t];
    ws[QFP_OFF + k * 512 + t] = a;
}

// ---- k3: qf = bq2 + sum partials; qkvec (pre-scaled); blocks 0-7 init V=bv, 8-15 row=bo ----
__global__ void k3_qkvec(const float* __restrict__ wk, const float* __restrict__ bq2,
                         const float* __restrict__ bv, const float* __restrict__ bo, float* ws) {
    __shared__ float qf[512];
    int t = threadIdx.x, bid = blockIdx.x;
    for (int o = t; o < 512; o += 256) {
        float s = bq2[o];
        for (int k = 0; k < 53; ++k) s += ws[QFP_OFF + k * 512 + o];
        qf[o] = s;
    }
    __syncthreads();
    int idx = bid * 256 + t;
    int h = idx >> 9, c = idx & 511;
    float a = 0.f;
#pragma unroll 8
    for (int e = 0; e < 64; ++e) a += qf[h * 64 + e] * wk[(size_t)c * 512 + h * 64 + e];
    ws[QKV_OFF + idx] = 0.125f * a;
    if (bid < 8) {
        ws[V_OFF + bid * 512 + t]       = bv[t];
        ws[V_OFF + bid * 512 + 256 + t] = bv[256 + t];
    } else {
        int b = bid - 8;
        ws[ROW_OFF + b * 512 + t]       = bo[t];
        ws[ROW_OFF + b * 512 + 256 + t] = bo[256 + t];
    }
}

// ---- kF: fused pass, 4 heads/wave (two wave-groups share row streams via cache) ----
// Per-wave live set ~92 VGPR -> fits the 128-reg tier => 4 waves/SIMD, no spill.
__global__ __launch_bounds__(512, 4) void kF(const float* __restrict__ x, float* __restrict__ ws) {
    int t = threadIdx.x;
    int lane = t & 63, w = t >> 6;        // 8 waves
    int wl = w & 3;                       // row-stream index 0..3
    int hbase = (w >> 2) * 4;             // head group: waves 0-3 -> h0..3, waves 4-7 -> h4..7
    int b = blockIdx.x >> 6, slot = blockIdx.x & 63;
    int wslot = slot * 4 + wl;            // 0..255 row streams per batch

    float4 qa[4], qb[4];
    const float4* qk4 = (const float4*)(ws + QKV_OFF);
#pragma unroll
    for (int h = 0; h < 4; ++h) {
        qa[h] = qk4[(hbase + h) * 128 + lane * 2];
        qb[h] = qk4[(hbase + h) * 128 + lane * 2 + 1];
    }

    float num[4][8] = {{0.f}};
    float den[4] = {0.f};

    const float4* xp = (const float4*)(x + (size_t)b * L_SEQ * 512);
    float4 cxa = xp[(size_t)wslot * 128 + lane * 2];
    float4 cxb = xp[(size_t)wslot * 128 + lane * 2 + 1];

    for (int r = wslot, it = 0; r < L_SEQ; r += 256, ++it) {
        int rn = r + 256;
        float4 nxa = cxa, nxb = cxb;
        if (rn < L_SEQ) {
            nxa = xp[(size_t)rn * 128 + lane * 2];
            nxb = xp[(size_t)rn * 128 + lane * 2 + 1];
        }
        float p[4];
#pragma unroll
        for (int h = 0; h < 4; ++h)
            p[h] = cxa.x * qa[h].x + cxa.y * qa[h].y + cxa.z * qa[h].z + cxa.w * qa[h].w
                 + cxb.x * qb[h].x + cxb.y * qb[h].y + cxb.z * qb[h].z + cxb.w * qb[h].w;
#pragma unroll
        for (int m = 32; m >= 1; m >>= 1) {
#pragma unroll
            for (int h = 0; h < 4; ++h) p[h] += __shfl_xor(p[h], m, 64);
        }
#pragma unroll
        for (int h = 0; h < 4; ++h) {
            float wg = __expf(p[h]);      // logits pre-scaled by 0.125; |p| small, no max needed
            den[h] += wg;
            num[h][0] += wg * cxa.x; num[h][1] += wg * cxa.y;
            num[h][2] += wg * cxa.z; num[h][3] += wg * cxa.w;
            num[h][4] += wg * cxb.x; num[h][5] += wg * cxb.y;
            num[h][6] += wg * cxb.z; num[h][7] += wg * cxb.w;
        }
        cxa = nxa; cxb = nxb;
        if ((it & 15) == 15) __syncthreads();   // bound wave drift -> L1/L2 reuse of shared rows
    }

    // staged deterministic block reduction; the two head-groups write disjoint halves
    __shared__ float num_s[4096];
    __shared__ float den_s[8];
    for (int wi = 0; wi < 4; ++wi) {
        if (wl == wi) {
#pragma unroll
            for (int hh = 0; hh < 4; ++hh) {
                int base = (hbase + hh) * 512 + lane * 8;
                if (wi == 0) {
#pragma unroll
                    for (int j = 0; j < 8; ++j) num_s[base + j] = num[hh][j];
                    if (lane == 0) den_s[hbase + hh] = den[hh];
                } else {
#pragma unroll
                    for (int j = 0; j < 8; ++j) num_s[base + j] += num[hh][j];
                    if (lane == 0) den_s[hbase + hh] += den[hh];
                }
            }
        }
        __syncthreads();
    }
    // coalesced partial-slot store (no atomics)
    float4* yp4 = (float4*)(ws + YPART_OFF + (size_t)blockIdx.x * 4096);
    const float4* ns4 = (const float4*)num_s;
    yp4[t]       = ns4[t];
    yp4[512 + t] = ns4[512 + t];
    if (t < 8) ws[DPART_OFF + blockIdx.x * 8 + t] = den_s[t];
}

// ---- kV: reduce 64 partial slots, normalize, V[b,o] += chunk GEMV (V init'd to bv) ----
__global__ __launch_bounds__(512) void kV(const float* __restrict__ wv, float* ws) {
    __shared__ float red[512];
    __shared__ float yn_s[512];   // [h][64c] for this chunk
    __shared__ float dinv[8];
    int b = blockIdx.x >> 3, cc = blockIdx.x & 7;
    int c0 = cc * 64;
    int t = threadIdx.x;
    // den: 64 slots x 8 heads
    red[t] = ws[DPART_OFF + (size_t)(b * 64 + (t >> 3)) * 8 + (t & 7)];
    __syncthreads();
#pragma unroll
    for (int off = 256; off >= 8; off >>= 1) {
        if (t < off) red[t] += red[t + off];
        __syncthreads();
    }
    if (t < 8) dinv[t] = 1.f / red[t];
    // y: sum 64 slots for this (h, c)
    int h = t >> 6, cl = t & 63;
    float s = 0.f;
    const float* yp = ws + YPART_OFF + (size_t)(b * 64) * 4096 + h * 512 + c0 + cl;
#pragma unroll 8
    for (int sl = 0; sl < 64; ++sl) s += yp[(size_t)sl * 4096];
    __syncthreads();
    yn_s[t] = s * dinv[h];
    __syncthreads();
    int o = t, ho = o >> 6;
    const float* yh = yn_s + ho * 64;
    float acc = 0.f;
#pragma unroll 8
    for (int ci = 0; ci < 64; ++ci) acc += yh[ci] * wv[(size_t)(c0 + ci) * 512 + o];
    atomicAdd(ws + V_OFF + b * 512 + o, acc);
}

// ---- kRow: row[b,j] += sum_{o in chunk} V[b,o]*wo[o,j]  (row init'd to bo) ----
__global__ __launch_bounds__(512) void kRow(const float* __restrict__ wo, float* ws) {
    __shared__ float V_s[64];
    int b = blockIdx.x >> 3, oc = blockIdx.x & 7;
    int o0 = oc * 64;
    int t = threadIdx.x;
    if (t < 64) V_s[t] = ws[V_OFF + b * 512 + o0 + t];
    __syncthreads();
    float acc = 0.f;
#pragma unroll 8
    for (int oi = 0; oi < 64; ++oi) acc += V_s[oi] * wo[(size_t)(o0 + oi) * 512 + t];
    atomicAdd(ws + ROW_OFF + b * 512 + t, acc);
}

// ---- k9: broadcast out[b,l,:] = row[b,:]  (nontemporal float4 stores) ----
__global__ __launch_bounds__(256) void k9_out(const float* __restrict__ ws, float* __restrict__ out) {
    const f4v* row4 = (const f4v*)(ws + ROW_OFF);
    f4v* out4 = (f4v*)out;
    size_t stride = (size_t)gridDim.x * blockDim.x;
    for (size_t g = (size_t)blockIdx.x * blockDim.x + threadIdx.x; g < 8388608ull; g += stride) {
        int b = (int)(g >> 20);          // 8192 rows * 128 float4/row = 2^20 per batch
        int q = (int)(g & 127);
        f4v v = row4[b * 128 + q];
        __builtin_nontemporal_store(v, &out4[g]);
    }
}

extern "C" void kernel_launch(void* const* d_in, const int* in_sizes, int n_in,
                              void* d_out, int out_size, void* d_ws, size_t ws_size,
                              hipStream_t stream) {
    const float* x   = (const float*)d_in[0];
    const float* poi = (const float*)d_in[1];
    const float* wq1 = (const float*)d_in[2];
    const float* bq1 = (const float*)d_in[3];
    const float* wq2 = (const float*)d_in[4];
    const float* bq2 = (const float*)d_in[5];
    const float* wk  = (const float*)d_in[6];
    const float* bk  = (const float*)d_in[7];
    const float* wv  = (const float*)d_in[8];
    const float* bv  = (const float*)d_in[9];
    const float* wo  = (const float*)d_in[10];
    const float* bo  = (const float*)d_in[11];
    float* ws  = (float*)d_ws;
    float* out = (float*)d_out;
    (void)bk;

    k2_qf<<<53, 512, 0, stream>>>(poi, wq1, bq1, wq2, ws);
    k3_qkvec<<<16, 256, 0, stream>>>(wk, bq2, bv, bo, ws);
    kF<<<512, 512, 0, stream>>>(x, ws);
    kV<<<64, 512, 0, stream>>>(wv, ws);
    kRow<<<64, 512, 0, stream>>>(wo, ws);
    k9_out<<<2048, 256, 0, stream>>>(ws, out);
}